// Round 1
// baseline (452.406 us; speedup 1.0000x reference)
//
#include <hip/hip_runtime.h>

// RetNet retention (diagonal state): per-channel linear scan over S.
// B=4, S=4096, D=2048, H=16, hd=128. fp32 in/out.
//
// Two-pass chunked scan, occupancy-first rewrite:
//  - KC=256 chunks (KL=16): 2048 blocks (8 blocks/CU) vs old 512 (2/CU).
//    Old version was latency-bound: 19% occupancy, VGPR=28 -> only ~2 loads
//    in flight per wave -> 2.8 TB/s effective.
//  - Explicit 4-step register batches (8-12 float4 loads issued before the
//    dependent FMA chain) restore memory-level parallelism.
//  - Carry scan truncated adaptively: weight of chunk c-1-j is dL^j (dL=d^KL);
//    terms below 1e-10 are dropped (exact full scan kept when decay ~ 1).
//  - ws_size-guarded: needs 8 MiB workspace; falls back to KL=64 otherwise.

namespace {

constexpr int kBlk = 256;
constexpr int kB   = 4;
constexpr int kS   = 4096;
constexpr int kD   = 2048;
constexpr int kRow = kD / 4;     // 512 float4 per (b,s) row
constexpr int kNG  = kB * kRow;  // 2048 float4-groups (b, j4)

template <int KL>
__global__ __launch_bounds__(kBlk, 8) void chunk_state_kernel(
    const float4* __restrict__ k, const float4* __restrict__ v,
    const float* __restrict__ decay, float4* __restrict__ A) {
  const int tid = blockIdx.x * kBlk + threadIdx.x;
  const int g   = tid & (kNG - 1);
  const int c   = tid >> 11;                 // tid / kNG
  const int b   = g >> 9;                    // g / kRow
  const int j4  = g & (kRow - 1);
  const float d = decay[j4 >> 5];            // head = (j4*4)/128

  const float4* kp = k + (b * kS + c * KL) * kRow + j4;
  const float4* vp = v + (b * kS + c * KL) * kRow + j4;
  float4 r = make_float4(0.f, 0.f, 0.f, 0.f);
#pragma unroll 4
  for (int ii = 0; ii < KL / 4; ++ii) {
    // batch all 8 loads before the dependent chain -> MLP
    float4 k0 = kp[0 * kRow], k1 = kp[1 * kRow], k2 = kp[2 * kRow], k3 = kp[3 * kRow];
    float4 v0 = vp[0 * kRow], v1 = vp[1 * kRow], v2 = vp[2 * kRow], v3 = vp[3 * kRow];
    kp += 4 * kRow;
    vp += 4 * kRow;
    r.x = fmaf(d, r.x, k0.x * v0.x);
    r.y = fmaf(d, r.y, k0.y * v0.y);
    r.z = fmaf(d, r.z, k0.z * v0.z);
    r.w = fmaf(d, r.w, k0.w * v0.w);
    r.x = fmaf(d, r.x, k1.x * v1.x);
    r.y = fmaf(d, r.y, k1.y * v1.y);
    r.z = fmaf(d, r.z, k1.z * v1.z);
    r.w = fmaf(d, r.w, k1.w * v1.w);
    r.x = fmaf(d, r.x, k2.x * v2.x);
    r.y = fmaf(d, r.y, k2.y * v2.y);
    r.z = fmaf(d, r.z, k2.z * v2.z);
    r.w = fmaf(d, r.w, k2.w * v2.w);
    r.x = fmaf(d, r.x, k3.x * v3.x);
    r.y = fmaf(d, r.y, k3.y * v3.y);
    r.z = fmaf(d, r.z, k3.z * v3.z);
    r.w = fmaf(d, r.w, k3.w * v3.w);
  }
  A[c * kNG + g] = r;
}

template <int KL>
__global__ __launch_bounds__(kBlk, 4) void retention_out_kernel(
    const float4* __restrict__ q, const float4* __restrict__ k,
    const float4* __restrict__ v, const float* __restrict__ decay,
    const float4* __restrict__ A, float4* __restrict__ out) {
  const int tid = blockIdx.x * kBlk + threadIdx.x;
  const int g   = tid & (kNG - 1);
  const int c   = tid >> 11;
  const int b   = g >> 9;
  const int j4  = g & (kRow - 1);
  const float d = decay[j4 >> 5];

  // dL = d^KL via squarings
  float dL = d;
  constexpr int kLog = (KL == 16) ? 4 : 6;
#pragma unroll
  for (int t = 0; t < kLog; ++t) dL *= dL;

  // Number of carry terms actually needed: weight of A[c-1-j] is dL^j.
  // Keep n terms with dL^n <= 1e-10 (dropped tail < 1e-10 * |state|).
  // Full scan when dL ~ 1 (e.g. decay very close to 1) -> always correct.
  int n = c;
  if (c > 0 && dL < 0.999999f) {
    float l = __logf(fmaxf(dL, 1e-37f));
    int need = (int)ceilf(-23.0259f / l);  // ln(1e-10) = -23.0259
    n = need < 1 ? 1 : (need < c ? need : c);
  }

  // carry = state at end of chunk c-1 (truncated scan of A with factor dL)
  float4 r = make_float4(0.f, 0.f, 0.f, 0.f);
  const float4* ap = A + (c - n) * kNG + g;
#pragma unroll 2
  for (int i = 0; i < n; ++i) {
    float4 a = ap[0];
    ap += kNG;
    r.x = fmaf(dL, r.x, a.x);
    r.y = fmaf(dL, r.y, a.y);
    r.z = fmaf(dL, r.z, a.z);
    r.w = fmaf(dL, r.w, a.w);
  }

  const int base = (b * kS + c * KL) * kRow + j4;
  const float4* qp = q + base;
  const float4* kp = k + base;
  const float4* vp = v + base;
  float4* op = out + base;
#pragma unroll 4
  for (int ii = 0; ii < KL / 4; ++ii) {
    // batch all 12 loads up front -> MLP
    float4 q0 = qp[0 * kRow], q1 = qp[1 * kRow], q2 = qp[2 * kRow], q3 = qp[3 * kRow];
    float4 k0 = kp[0 * kRow], k1 = kp[1 * kRow], k2 = kp[2 * kRow], k3 = kp[3 * kRow];
    float4 v0 = vp[0 * kRow], v1 = vp[1 * kRow], v2 = vp[2 * kRow], v3 = vp[3 * kRow];
    qp += 4 * kRow;
    kp += 4 * kRow;
    vp += 4 * kRow;
    float4 o;
    // step 0
    r.x = fmaf(d, r.x, k0.x * v0.x);
    r.y = fmaf(d, r.y, k0.y * v0.y);
    r.z = fmaf(d, r.z, k0.z * v0.z);
    r.w = fmaf(d, r.w, k0.w * v0.w);
    o.x = q0.x * r.x; o.y = q0.y * r.y; o.z = q0.z * r.z; o.w = q0.w * r.w;
    op[0 * kRow] = o;
    // step 1
    r.x = fmaf(d, r.x, k1.x * v1.x);
    r.y = fmaf(d, r.y, k1.y * v1.y);
    r.z = fmaf(d, r.z, k1.z * v1.z);
    r.w = fmaf(d, r.w, k1.w * v1.w);
    o.x = q1.x * r.x; o.y = q1.y * r.y; o.z = q1.z * r.z; o.w = q1.w * r.w;
    op[1 * kRow] = o;
    // step 2
    r.x = fmaf(d, r.x, k2.x * v2.x);
    r.y = fmaf(d, r.y, k2.y * v2.y);
    r.z = fmaf(d, r.z, k2.z * v2.z);
    r.w = fmaf(d, r.w, k2.w * v2.w);
    o.x = q2.x * r.x; o.y = q2.y * r.y; o.z = q2.z * r.z; o.w = q2.w * r.w;
    op[2 * kRow] = o;
    // step 3
    r.x = fmaf(d, r.x, k3.x * v3.x);
    r.y = fmaf(d, r.y, k3.y * v3.y);
    r.z = fmaf(d, r.z, k3.z * v3.z);
    r.w = fmaf(d, r.w, k3.w * v3.w);
    o.x = q3.x * r.x; o.y = q3.y * r.y; o.z = q3.z * r.z; o.w = q3.w * r.w;
    op[3 * kRow] = o;
    op += 4 * kRow;
  }
}

}  // namespace

extern "C" void kernel_launch(void* const* d_in, const int* in_sizes, int n_in,
                              void* d_out, int out_size, void* d_ws, size_t ws_size,
                              hipStream_t stream) {
  const float4* q     = (const float4*)d_in[0];
  const float4* k     = (const float4*)d_in[1];
  const float4* v     = (const float4*)d_in[2];
  const float*  decay = (const float*)d_in[3];
  float4* out = (float4*)d_out;
  float4* A   = (float4*)d_ws;

  const size_t needA = (size_t)(kS / 16) * kNG * sizeof(float4);  // 8 MiB
  if (ws_size >= needA) {
    constexpr int KL = 16;                                  // 256 chunks
    const int nblocks = kNG * (kS / KL) / kBlk;             // 2048 blocks
    chunk_state_kernel<KL><<<nblocks, kBlk, 0, stream>>>(k, v, decay, A);
    retention_out_kernel<KL><<<nblocks, kBlk, 0, stream>>>(q, k, v, decay, A, out);
  } else {
    constexpr int KL = 64;                                  // legacy 64 chunks, 2 MiB
    const int nblocks = kNG * (kS / KL) / kBlk;             // 512 blocks
    chunk_state_kernel<KL><<<nblocks, kBlk, 0, stream>>>(k, v, decay, A);
    retention_out_kernel<KL><<<nblocks, kBlk, 0, stream>>>(q, k, v, decay, A, out);
  }
}

// Round 2
// 446.429 us; speedup vs baseline: 1.0134x; 1.0134x over previous
//
#include <hip/hip_runtime.h>

// RetNet retention (diagonal state): per-channel linear scan over S.
// B=4, S=4096, D=2048, H=16, hd=128. fp32 in/out.
//
// Two-pass chunked scan. Round-2 theory: kernel A was MLP-starved
// (VGPR=28..32 -> ~2 loads in flight -> 2.6 TB/s effective), NOT
// occupancy-starved (round 1: occupancy 19->61%, dur unchanged).
// Fix: preload a full 16-step group (32 float4 = 128 VGPRs) as one
// block of independent loads, pinned with sched_barrier(0) so the
// register allocator can't sink them back into the FMA chain.
// retention_out already runs >=5.2 TB/s; same treatment applied there,
// with the k,v preload issued BEFORE the carry loop so the L2 carry
// reads overlap the HBM streams.

namespace {

constexpr int kBlk = 256;
constexpr int kB   = 4;
constexpr int kS   = 4096;
constexpr int kD   = 2048;
constexpr int kRow = kD / 4;     // 512 float4 per (b,s) row
constexpr int kNG  = kB * kRow;  // 2048 float4-groups (b, j4)
constexpr int kGrp = 16;         // steps per register-preload group

template <int KL>
__global__ __launch_bounds__(kBlk) void chunk_state_kernel(
    const float4* __restrict__ k, const float4* __restrict__ v,
    const float* __restrict__ decay, float4* __restrict__ A) {
  const int tid = blockIdx.x * kBlk + threadIdx.x;
  const int g   = tid & (kNG - 1);
  const int c   = tid >> 11;                 // tid / kNG
  const int b   = g >> 9;                    // g / kRow
  const int j4  = g & (kRow - 1);
  const float d = decay[j4 >> 5];            // head = (j4*4)/128

  const float4* kp = k + (b * kS + c * KL) * kRow + j4;
  const float4* vp = v + (b * kS + c * KL) * kRow + j4;
  float4 r = make_float4(0.f, 0.f, 0.f, 0.f);

#pragma unroll
  for (int grp = 0; grp < KL / kGrp; ++grp) {
    // Issue all 32 loads of this group before any consumption.
    float4 kr[kGrp], vr[kGrp];
#pragma unroll
    for (int i = 0; i < kGrp; ++i) {
      kr[i] = kp[i * kRow];
      vr[i] = vp[i * kRow];
    }
    __builtin_amdgcn_sched_barrier(0);  // don't sink loads into the chain
    kp += kGrp * kRow;
    vp += kGrp * kRow;
#pragma unroll
    for (int i = 0; i < kGrp; ++i) {
      r.x = fmaf(d, r.x, kr[i].x * vr[i].x);
      r.y = fmaf(d, r.y, kr[i].y * vr[i].y);
      r.z = fmaf(d, r.z, kr[i].z * vr[i].z);
      r.w = fmaf(d, r.w, kr[i].w * vr[i].w);
    }
  }
  A[c * kNG + g] = r;
}

template <int KL>
__global__ __launch_bounds__(kBlk) void retention_out_kernel(
    const float4* __restrict__ q, const float4* __restrict__ k,
    const float4* __restrict__ v, const float* __restrict__ decay,
    const float4* __restrict__ A, float4* __restrict__ out) {
  const int tid = blockIdx.x * kBlk + threadIdx.x;
  const int g   = tid & (kNG - 1);
  const int c   = tid >> 11;
  const int b   = g >> 9;
  const int j4  = g & (kRow - 1);
  const float d = decay[j4 >> 5];

  // dL = d^KL via squarings
  float dL = d;
  constexpr int kLog = (KL == 16) ? 4 : 6;
#pragma unroll
  for (int t = 0; t < kLog; ++t) dL *= dL;

  // Truncated carry: weight of A[c-1-j] is dL^j; keep n with dL^n <= 1e-10.
  // Full scan when dL ~ 1 -> always correct for decay near 1.
  int n = c;
  if (c > 0 && dL < 0.999999f) {
    float l = __logf(fmaxf(dL, 1e-37f));
    int need = (int)ceilf(-23.0259f / l);  // ln(1e-10) = -23.0259
    n = need < 1 ? 1 : (need < c ? need : c);
  }

  const int base = (b * kS + c * KL) * kRow + j4;
  const float4* qp = q + base;
  const float4* kp = k + base;
  const float4* vp = v + base;
  float4* op = out + base;

  // Preload group 0 of k,v NOW so the HBM streams are in flight while the
  // (L2-resident) carry loop runs.
  float4 kr[kGrp], vr[kGrp];
#pragma unroll
  for (int i = 0; i < kGrp; ++i) {
    kr[i] = kp[i * kRow];
    vr[i] = vp[i * kRow];
  }
  __builtin_amdgcn_sched_barrier(0);

  // carry = state at end of chunk c-1 (truncated scan of A with factor dL)
  float4 r = make_float4(0.f, 0.f, 0.f, 0.f);
  const float4* ap = A + (c - n) * kNG + g;
  for (int i = 0; i < n; ++i) {
    float4 a = ap[0];
    ap += kNG;
    r.x = fmaf(dL, r.x, a.x);
    r.y = fmaf(dL, r.y, a.y);
    r.z = fmaf(dL, r.z, a.z);
    r.w = fmaf(dL, r.w, a.w);
  }

#pragma unroll
  for (int grp = 0; grp < KL / kGrp; ++grp) {
    if (grp > 0) {
      // Fallback (KL=64) path: reload next group. Primary KL=16 path has
      // exactly one group and never takes this branch.
#pragma unroll
      for (int i = 0; i < kGrp; ++i) {
        kr[i] = kp[grp * kGrp * kRow + i * kRow];
        vr[i] = vp[grp * kGrp * kRow + i * kRow];
      }
      __builtin_amdgcn_sched_barrier(0);
    }
#pragma unroll
    for (int i = 0; i < kGrp; ++i) {
      float4 qq = qp[(grp * kGrp + i) * kRow];
      r.x = fmaf(d, r.x, kr[i].x * vr[i].x);
      r.y = fmaf(d, r.y, kr[i].y * vr[i].y);
      r.z = fmaf(d, r.z, kr[i].z * vr[i].z);
      r.w = fmaf(d, r.w, kr[i].w * vr[i].w);
      float4 o;
      o.x = qq.x * r.x;
      o.y = qq.y * r.y;
      o.z = qq.z * r.z;
      o.w = qq.w * r.w;
      op[(grp * kGrp + i) * kRow] = o;
    }
  }
}

}  // namespace

extern "C" void kernel_launch(void* const* d_in, const int* in_sizes, int n_in,
                              void* d_out, int out_size, void* d_ws, size_t ws_size,
                              hipStream_t stream) {
  const float4* q     = (const float4*)d_in[0];
  const float4* k     = (const float4*)d_in[1];
  const float4* v     = (const float4*)d_in[2];
  const float*  decay = (const float*)d_in[3];
  float4* out = (float4*)d_out;
  float4* A   = (float4*)d_ws;

  const size_t needA = (size_t)(kS / 16) * kNG * sizeof(float4);  // 8 MiB
  if (ws_size >= needA) {
    constexpr int KL = 16;                                  // 256 chunks
    const int nblocks = kNG * (kS / KL) / kBlk;             // 2048 blocks
    chunk_state_kernel<KL><<<nblocks, kBlk, 0, stream>>>(k, v, decay, A);
    retention_out_kernel<KL><<<nblocks, kBlk, 0, stream>>>(q, k, v, decay, A, out);
  } else {
    constexpr int KL = 64;                                  // legacy 2 MiB path
    const int nblocks = kNG * (kS / KL) / kBlk;             // 512 blocks
    chunk_state_kernel<KL><<<nblocks, kBlk, 0, stream>>>(k, v, decay, A);
    retention_out_kernel<KL><<<nblocks, kBlk, 0, stream>>>(q, k, v, decay, A, out);
  }
}